// Round 2
// baseline (217.754 us; speedup 1.0000x reference)
//
#include <hip/hip_runtime.h>
#include <hip/hip_bf16.h>
#include <math.h>

typedef __bf16 bf16_t;
typedef __bf16 bf16x8 __attribute__((ext_vector_type(8)));
typedef float f32x4 __attribute__((ext_vector_type(4)));

#define NPOS 4096

__device__ __forceinline__ f32x4 mfma16(bf16x8 a, bf16x8 b, f32x4 c) {
    return __builtin_amdgcn_mfma_f32_16x16x32_bf16(a, b, c, 0, 0, 0);
}

// Stage a tile into LDS with row-XOR swizzle (byte ^= (row&7)<<4).
// RB = LDS row bytes (pow2). BYTES = total tile bytes (multiple of 4096).
// srcStride = global row stride in bytes (== RB when tile is contiguous).
template<int RB, int BYTES>
__device__ __forceinline__ void stage_tile(const char* __restrict__ src,
                                           char* __restrict__ lds,
                                           int srcStride, int tid)
{
#pragma unroll
    for (int j0 = 0; j0 < BYTES; j0 += 4096) {
        int j = j0 + tid * 16;
        int row = j / RB;
        int col = j & (RB - 1);
        float4 v = *(const float4*)(src + (size_t)row * srcStride + col);
        *(float4*)(lds + row * RB + (col ^ ((row & 7) << 4))) = v;
    }
}

// ---------------- transpose + fp32->bf16 convert ----------------
// features [B][C][N] fp32  ->  ft [B][N][C] bf16
__global__ __launch_bounds__(256) void k_transpose(const float* __restrict__ s2d,
                                                   const float* __restrict__ s3d,
                                                   bf16_t* __restrict__ d2d,
                                                   bf16_t* __restrict__ d3d)
{
    __shared__ float tile[64][65];
    int bid = blockIdx.x, tid = threadIdx.x;
    const float* src; bf16_t* dst; int C, b, c0, n0;
    if (bid < 1024) { src = s2d; dst = d2d; C = 256; b = bid >> 8; c0 = ((bid >> 6) & 3) << 6; n0 = (bid & 63) << 6; }
    else { int r = bid - 1024; src = s3d; dst = d3d; C = 128; b = r >> 7; c0 = ((r >> 6) & 1) << 6; n0 = (r & 63) << 6; }
    const float* sp = src + ((size_t)b * C + c0) * NPOS + n0;
#pragma unroll
    for (int i = 0; i < 16; i++) {
        int idx = tid + i * 256; int c = idx >> 6, n = idx & 63;
        tile[c][n] = sp[(size_t)c * NPOS + n];
    }
    __syncthreads();
    bf16_t* dp = dst + ((size_t)b * NPOS + n0) * C + c0;
#pragma unroll
    for (int i = 0; i < 16; i++) {
        int idx = tid + i * 256; int n = idx >> 6, c = idx & 63;
        dp[(size_t)n * C + c] = (bf16_t)tile[c][n];
    }
}

// ---------------- weight fp32->bf16 ----------------
__global__ __launch_bounds__(256) void k_weights(const float* w0, const float* w1, const float* w2, const float* w3,
                                                 const float* w4, const float* w5, const float* w6, const float* w7,
                                                 bf16_t* dst)
{
    int i = blockIdx.x * 256 + threadIdx.x;
    if      (i <  32768) dst[i] = (bf16_t)w0[i];
    else if (i <  49152) dst[i] = (bf16_t)w1[i - 32768];
    else if (i <  65536) dst[i] = (bf16_t)w2[i - 49152];
    else if (i <  98304) dst[i] = (bf16_t)w3[i - 65536];
    else if (i < 106496) dst[i] = (bf16_t)w4[i - 98304];
    else if (i < 122880) dst[i] = (bf16_t)w5[i - 106496];
    else if (i < 139264) dst[i] = (bf16_t)w6[i - 122880];
    else if (i < 147456) dst[i] = (bf16_t)w7[i - 139264];
}

// ---------------- projection GEMM ----------------
// Xt: [B][N][K] bf16. W: [M][K] bf16. MODE 0: out[B][N][M] bf16 = (Xt@W^T + b)*scale
// MODE 1: out[B][M][N] bf16 = W@Xt^T + b.  MODE 2: out[B][M][N] f32 = W@Xt^T + b + resid.
template<int K, int M, int MODE>
__global__ __launch_bounds__(256, 2) void k_proj(const bf16_t* __restrict__ Xt,
                                                 const bf16_t* __restrict__ W,
                                                 const float* __restrict__ bias,
                                                 float scale,
                                                 const float* __restrict__ resid,
                                                 void* __restrict__ outp)
{
    extern __shared__ char smem[];
    constexpr int RB = K * 2;
    int bid = blockIdx.x, tid = threadIdx.x;
    int b = bid >> 6, n0 = (bid & 63) << 6;
    int wave = tid >> 6, lane = tid & 63, g = lane >> 4, lr = lane & 15;

    stage_tile<RB, 64 * RB>((const char*)(Xt + ((size_t)b * NPOS + n0) * K), smem, RB, tid);
    __syncthreads();

    f32x4 acc[M / 16];
#pragma unroll
    for (int ob = 0; ob < M / 16; ++ob) acc[ob] = f32x4{0.f, 0.f, 0.f, 0.f};
    int xrow = wave * 16 + lr;
#pragma unroll
    for (int ks = 0; ks < K / 32; ++ks) {
        bf16x8 xf = *(const bf16x8*)(smem + xrow * RB + ((((ks * 32 + g * 8) * 2)) ^ ((xrow & 7) << 4)));
#pragma unroll
        for (int ob = 0; ob < M / 16; ++ob) {
            bf16x8 wf = *(const bf16x8*)(W + (size_t)(ob * 16 + lr) * K + ks * 32 + g * 8);
            if constexpr (MODE == 0) acc[ob] = mfma16(xf, wf, acc[ob]);
            else                     acc[ob] = mfma16(wf, xf, acc[ob]);
        }
    }
    if constexpr (MODE == 0) {
        bf16_t* out = (bf16_t*)outp;
#pragma unroll
        for (int ob = 0; ob < M / 16; ++ob) {
            int o = ob * 16 + lr;
            float bs = bias[o];
#pragma unroll
            for (int r = 0; r < 4; r++) {
                size_t n = (size_t)b * NPOS + n0 + wave * 16 + g * 4 + r;
                out[n * M + o] = (bf16_t)((acc[ob][r] + bs) * scale);
            }
        }
    } else {
#pragma unroll
        for (int ob = 0; ob < M / 16; ++ob) {
#pragma unroll
            for (int r = 0; r < 4; r++) {
                int o = ob * 16 + g * 4 + r;
                size_t idx = ((size_t)b * M + o) * NPOS + n0 + wave * 16 + lr;
                float v = acc[ob][r] + bias[o];
                if constexpr (MODE == 1) ((bf16_t*)outp)[idx] = (bf16_t)v;
                else                     ((float*)outp)[idx] = v + resid[idx];
            }
        }
    }
}

// ---------------- fused flash attention ----------------
// Qt,Kt: [B][N][D] bf16 (Q pre-scaled by D^-0.5). V: [B][D][N] bf16. Ot: [B][N][D] bf16.
template<int D>
__device__ __forceinline__ void attn_body(const bf16_t* __restrict__ Qt,
                                          const bf16_t* __restrict__ Kt,
                                          const bf16_t* __restrict__ V,
                                          bf16_t* __restrict__ Ot,
                                          int b, int qt, char* smem, int tid)
{
    constexpr int RB = D * 2;
    char* Qs = smem;                 // 64*RB
    char* Ks = smem + 64 * RB;       // 64*RB
    char* Vs = Ks + 64 * RB;         // D*128
    char* Ps = Vs + D * 128;         // 4 waves * 16*64*2
    int wave = tid >> 6, lane = tid & 63, g = lane >> 4, lr = lane & 15;
    char* Pw = Ps + wave * 2048;

    stage_tile<RB, 64 * RB>((const char*)(Qt + ((size_t)b * NPOS + qt * 64) * D), Qs, RB, tid);

    f32x4 acc[D / 16];
#pragma unroll
    for (int cb = 0; cb < D / 16; cb++) acc[cb] = f32x4{0.f, 0.f, 0.f, 0.f};
    float m_r[4] = {-INFINITY, -INFINITY, -INFINITY, -INFINITY};
    float l_r[4] = {0.f, 0.f, 0.f, 0.f};

    const char* kb = (const char*)(Kt + (size_t)b * NPOS * D);
    const char* vb = (const char*)(V + (size_t)b * D * NPOS);
    int qrow = wave * 16 + lr;

    for (int t = 0; t < 64; ++t) {
        stage_tile<RB, 64 * RB>(kb + (size_t)t * 64 * RB, Ks, RB, tid);
        stage_tile<128, D * 128>(vb + t * 128, Vs, NPOS * 2, tid);
        __syncthreads();

        // S = Q K^T  (16 q-rows per wave x 64 keys)
        bf16x8 a[D / 32];
#pragma unroll
        for (int ks = 0; ks < D / 32; ks++)
            a[ks] = *(const bf16x8*)(Qs + qrow * RB + (((ks * 32 + g * 8) * 2) ^ ((qrow & 7) << 4)));
        f32x4 s[4];
#pragma unroll
        for (int mb = 0; mb < 4; ++mb) {
            f32x4 sa = {0.f, 0.f, 0.f, 0.f};
#pragma unroll
            for (int ks = 0; ks < D / 32; ks++) {
                int mrow = mb * 16 + lr;
                bf16x8 kf = *(const bf16x8*)(Ks + mrow * RB + (((ks * 32 + g * 8) * 2) ^ ((mrow & 7) << 4)));
                sa = mfma16(a[ks], kf, sa);
            }
            s[mb] = sa;
        }
        // online softmax: row n = g*4 + r lives in 16 lanes (l>>4)==g, reg r
#pragma unroll
        for (int r = 0; r < 4; r++) {
            float mx = fmaxf(fmaxf(s[0][r], s[1][r]), fmaxf(s[2][r], s[3][r]));
            mx = fmaxf(mx, __shfl_xor(mx, 1));
            mx = fmaxf(mx, __shfl_xor(mx, 2));
            mx = fmaxf(mx, __shfl_xor(mx, 4));
            mx = fmaxf(mx, __shfl_xor(mx, 8));
            float mn = fmaxf(m_r[r], mx);
            float fc = __expf(m_r[r] - mn);
            m_r[r] = mn;
            float ps = 0.f;
#pragma unroll
            for (int mb = 0; mb < 4; ++mb) { float p = __expf(s[mb][r] - mn); s[mb][r] = p; ps += p; }
            ps += __shfl_xor(ps, 1);
            ps += __shfl_xor(ps, 2);
            ps += __shfl_xor(ps, 4);
            ps += __shfl_xor(ps, 8);
            l_r[r] = l_r[r] * fc + ps;
#pragma unroll
            for (int cb = 0; cb < D / 16; cb++) acc[cb][r] *= fc;
        }
        // P -> LDS (per-wave, swizzled) to convert D-frag layout to A-frag layout
#pragma unroll
        for (int mb = 0; mb < 4; ++mb)
#pragma unroll
            for (int r = 0; r < 4; r++) {
                int n = g * 4 + r;
                int cby = (mb * 16 + lr) * 2;
                *(bf16_t*)(Pw + n * 128 + (cby ^ ((n & 7) << 4))) = (bf16_t)s[mb][r];
            }
        // O^T += P @ V^T
#pragma unroll
        for (int kk = 0; kk < 2; ++kk) {
            bf16x8 pa = *(const bf16x8*)(Pw + lr * 128 + (((kk * 32 + g * 8) * 2) ^ ((lr & 7) << 4)));
#pragma unroll
            for (int cb = 0; cb < D / 16; ++cb) {
                int crow = cb * 16 + lr;
                bf16x8 vf = *(const bf16x8*)(Vs + crow * 128 + (((kk * 32 + g * 8) * 2) ^ ((crow & 7) << 4)));
                acc[cb] = mfma16(pa, vf, acc[cb]);
            }
        }
        __syncthreads();
    }
#pragma unroll
    for (int cb = 0; cb < D / 16; cb++)
#pragma unroll
        for (int r = 0; r < 4; r++) {
            size_t n = (size_t)b * NPOS + qt * 64 + wave * 16 + g * 4 + r;
            Ot[n * D + cb * 16 + lr] = (bf16_t)(acc[cb][r] / l_r[r]);
        }
}

__global__ __launch_bounds__(256, 2) void k_attn(const bf16_t* QtA, const bf16_t* KtA, const bf16_t* VA, bf16_t* OtA,
                                                 const bf16_t* QtB, const bf16_t* KtB, const bf16_t* VB, bf16_t* OtB)
{
    extern __shared__ char smem[];
    int bid = blockIdx.x, tid = threadIdx.x;
    if (bid < 256) attn_body<128>(QtA, KtA, VA, OtA, bid >> 6, bid & 63, smem, tid);
    else { int r = bid - 256; attn_body<64>(QtB, KtB, VB, OtB, r >> 6, r & 63, smem, tid); }
}

extern "C" void kernel_launch(void* const* d_in, const int* in_sizes, int n_in,
                              void* d_out, int out_size, void* d_ws, size_t ws_size,
                              hipStream_t stream)
{
    (void)in_sizes; (void)n_in; (void)out_size; (void)ws_size;
    const float* f2d = (const float*)d_in[0];
    const float* f3d = (const float*)d_in[1];
    const float* wqA = (const float*)d_in[2];  const float* bqA = (const float*)d_in[3];
    const float* wkA = (const float*)d_in[4];  const float* bkA = (const float*)d_in[5];
    const float* wvA = (const float*)d_in[6];  const float* bvA = (const float*)d_in[7];
    const float* wpA = (const float*)d_in[8];  const float* bpA = (const float*)d_in[9];
    const float* wqB = (const float*)d_in[10]; const float* bqB = (const float*)d_in[11];
    const float* wkB = (const float*)d_in[12]; const float* bkB = (const float*)d_in[13];
    const float* wvB = (const float*)d_in[14]; const float* bvB = (const float*)d_in[15];
    const float* wpB = (const float*)d_in[16]; const float* bpB = (const float*)d_in[17];

    char* ws = (char*)d_ws;
    bf16_t* ft2d = (bf16_t*)(ws);                // [B][N][256]  8388608 B
    bf16_t* ft3d = (bf16_t*)(ws + 8388608);      // [B][N][128]  4194304 B
    bf16_t* wbf  = (bf16_t*)(ws + 12582912);     // 147456 elems
    bf16_t* QtA  = (bf16_t*)(ws + 12877824);     // [B][N][128]
    bf16_t* KtA_ = (bf16_t*)(ws + 17072128);
    bf16_t* VA_  = (bf16_t*)(ws + 21266432);     // [B][128][N]
    bf16_t* QtB  = (bf16_t*)(ws + 25460736);     // [B][N][64]
    bf16_t* KtB_ = (bf16_t*)(ws + 27557888);
    bf16_t* VB_  = (bf16_t*)(ws + 29655040);     // [B][64][N]
    bf16_t* OtA  = (bf16_t*)(ws + 31752192);     // [B][N][128]
    bf16_t* OtB  = (bf16_t*)(ws + 35946496);     // [B][N][64]

    k_transpose<<<1536, 256, 0, stream>>>(f2d, f3d, ft2d, ft3d);
    k_weights<<<576, 256, 0, stream>>>(wqA, wkA, wvA, wpA, wqB, wkB, wvB, wpB, wbf);

    const float sA = 0.08838834764831845f;  // 128^-0.5
    const float sB = 0.125f;                // 64^-0.5

    k_proj<256, 128, 0><<<256, 256, 32768, stream>>>(ft2d, wbf +      0, bqA, sA,  nullptr, QtA);
    k_proj<128, 128, 0><<<256, 256, 16384, stream>>>(ft3d, wbf +  32768, bkA, 1.f, nullptr, KtA_);
    k_proj<128, 128, 1><<<256, 256, 16384, stream>>>(ft3d, wbf +  49152, bvA, 1.f, nullptr, VA_);
    k_proj<128,  64, 0><<<256, 256, 16384, stream>>>(ft3d, wbf +  98304, bqB, sB,  nullptr, QtB);
    k_proj<256,  64, 0><<<256, 256, 32768, stream>>>(ft2d, wbf + 106496, bkB, 1.f, nullptr, KtB_);
    k_proj<256,  64, 1><<<256, 256, 32768, stream>>>(ft2d, wbf + 122880, bvB, 1.f, nullptr, VB_);

    k_attn<<<512, 256, 57344, stream>>>(QtA, KtA_, VA_, OtA, QtB, KtB_, VB_, OtB);

    k_proj<128, 256, 2><<<256, 256, 16384, stream>>>(OtA, wbf +  65536, bpA, 1.f, f2d, (float*)d_out);
    k_proj< 64, 128, 2><<<256, 256,  8192, stream>>>(OtB, wbf + 139264, bpB, 1.f, f3d, (float*)d_out + 4194304);
}

// Round 3
// 195.725 us; speedup vs baseline: 1.1126x; 1.1126x over previous
//
#include <hip/hip_runtime.h>
#include <hip/hip_bf16.h>
#include <math.h>

typedef __bf16 bf16_t;
typedef __bf16 bf16x8 __attribute__((ext_vector_type(8)));
typedef float f32x4 __attribute__((ext_vector_type(4)));
typedef float f32x16 __attribute__((ext_vector_type(16)));
typedef unsigned u32x2 __attribute__((ext_vector_type(2)));

#define NPOS 4096

__device__ __forceinline__ f32x4 mfma16(bf16x8 a, bf16x8 b, f32x4 c) {
    return __builtin_amdgcn_mfma_f32_16x16x32_bf16(a, b, c, 0, 0, 0);
}
__device__ __forceinline__ f32x16 mfma32(bf16x8 a, bf16x8 b, f32x16 c) {
    return __builtin_amdgcn_mfma_f32_32x32x16_bf16(a, b, c, 0, 0, 0);
}

typedef __attribute__((address_space(1))) const unsigned gas_u32;
typedef __attribute__((address_space(3))) unsigned las_u32;

__device__ __forceinline__ void gl_lds16(const char* g, char* l) {
    __builtin_amdgcn_global_load_lds((gas_u32*)g, (las_u32*)l, 16, 0, 0);
}

// Async-stage a tile into LDS, linear dest + inverse-swizzled global source so that
// reads at lds[row*RB + (col ^ ((row&7)<<4))] see src[row][col].  (T2 + rule #21)
template<int RB, int NCH>
__device__ __forceinline__ void stage_swz(char* lds, const char* g, int srcStride, int w, int lane) {
#pragma unroll
    for (int c = 0; c < NCH; ++c) {
        int lb = (w * NCH + c) * 1024;
        int j = lb + lane * 16;
        int row = j / RB;
        int col = j & (RB - 1);
        gl_lds16(g + (size_t)row * srcStride + (col ^ ((row & 7) << 4)), lds + lb);
    }
}

template<int RB>
__device__ __forceinline__ bf16x8 ldfrag(const char* lds, int row, int colb) {
    return *(const bf16x8*)(lds + row * RB + (colb ^ ((row & 7) << 4)));
}

__device__ __forceinline__ unsigned pkbf(float a, float b) {
    union { bf16_t h[2]; unsigned u; } t;
    t.h[0] = (bf16_t)a; t.h[1] = (bf16_t)b;
    return t.u;
}

// Build PV A-fragment pa[ks] from exp'd scores (one 32-key block sb, reg base 0 or 8).
// Derivation: pa element j needs P[q][ks*16 + hi*8 + j] = s[reg=(j&3)+base+4*hi_dest] of
// half (j>>2). One permlane32_swap fills two output words (T12).
#define MKPA(sb, base) ({                                                   \
    unsigned a0_ = pkbf((sb)[(base)+0], (sb)[(base)+1]);                    \
    unsigned a1_ = pkbf((sb)[(base)+2], (sb)[(base)+3]);                    \
    unsigned a2_ = pkbf((sb)[(base)+4], (sb)[(base)+5]);                    \
    unsigned a3_ = pkbf((sb)[(base)+6], (sb)[(base)+7]);                    \
    u32x2 r0_ = __builtin_amdgcn_permlane32_swap(a2_, a0_, false, false);   \
    u32x2 r1_ = __builtin_amdgcn_permlane32_swap(a3_, a1_, false, false);   \
    union { unsigned u[4]; bf16x8 v; } pu_;                                 \
    pu_.u[0] = r0_.y; pu_.u[1] = r1_.y; pu_.u[2] = r0_.x; pu_.u[3] = r1_.x; \
    pu_.v; })

// ---------------- transpose + fp32->bf16 convert ----------------
__global__ __launch_bounds__(256) void k_transpose(const float* __restrict__ s2d,
                                                   const float* __restrict__ s3d,
                                                   bf16_t* __restrict__ d2d,
                                                   bf16_t* __restrict__ d3d)
{
    __shared__ float tile[64][65];
    int bid = blockIdx.x, tid = threadIdx.x;
    const float* src; bf16_t* dst; int C, b, c0, n0;
    if (bid < 1024) { src = s2d; dst = d2d; C = 256; b = bid >> 8; c0 = ((bid >> 6) & 3) << 6; n0 = (bid & 63) << 6; }
    else { int r = bid - 1024; src = s3d; dst = d3d; C = 128; b = r >> 7; c0 = ((r >> 6) & 1) << 6; n0 = (r & 63) << 6; }
    const float* sp = src + ((size_t)b * C + c0) * NPOS + n0;
#pragma unroll
    for (int i = 0; i < 16; i++) {
        int idx = tid + i * 256; int c = idx >> 6, n = idx & 63;
        tile[c][n] = sp[(size_t)c * NPOS + n];
    }
    __syncthreads();
    bf16_t* dp = dst + ((size_t)b * NPOS + n0) * C + c0;
#pragma unroll
    for (int i = 0; i < 16; i++) {
        int idx = tid + i * 256; int n = idx >> 6, c = idx & 63;
        dp[(size_t)n * C + c] = (bf16_t)tile[c][n];
    }
}

// ---------------- weight fp32->bf16 ----------------
__global__ __launch_bounds__(256) void k_weights(const float* w0, const float* w1, const float* w2, const float* w3,
                                                 const float* w4, const float* w5, const float* w6, const float* w7,
                                                 bf16_t* dst)
{
    int i = blockIdx.x * 256 + threadIdx.x;
    if      (i <  32768) dst[i] = (bf16_t)w0[i];
    else if (i <  49152) dst[i] = (bf16_t)w1[i - 32768];
    else if (i <  65536) dst[i] = (bf16_t)w2[i - 49152];
    else if (i <  98304) dst[i] = (bf16_t)w3[i - 65536];
    else if (i < 106496) dst[i] = (bf16_t)w4[i - 98304];
    else if (i < 122880) dst[i] = (bf16_t)w5[i - 106496];
    else if (i < 139264) dst[i] = (bf16_t)w6[i - 122880];
    else if (i < 147456) dst[i] = (bf16_t)w7[i - 139264];
}

// ---------------- projection GEMM ----------------
template<int K, int M, int MODE>
__global__ __launch_bounds__(256, 2) void k_proj(const bf16_t* __restrict__ Xt,
                                                 const bf16_t* __restrict__ W,
                                                 const float* __restrict__ bias,
                                                 float scale,
                                                 const float* __restrict__ resid,
                                                 void* __restrict__ outp)
{
    extern __shared__ char smem[];
    constexpr int RB = K * 2;
    int bid = blockIdx.x, tid = threadIdx.x;
    int b = bid >> 6, n0 = (bid & 63) << 6;
    int wave = tid >> 6, lane = tid & 63, g = lane >> 4, lr = lane & 15;

    {
        const char* src = (const char*)(Xt + ((size_t)b * NPOS + n0) * K);
#pragma unroll
        for (int j0 = 0; j0 < 64 * RB; j0 += 4096) {
            int j = j0 + tid * 16;
            int row = j / RB;
            int col = j & (RB - 1);
            float4 v = *(const float4*)(src + (size_t)row * RB + col);
            *(float4*)(smem + row * RB + (col ^ ((row & 7) << 4))) = v;
        }
    }
    __syncthreads();

    f32x4 acc[M / 16];
#pragma unroll
    for (int ob = 0; ob < M / 16; ++ob) acc[ob] = f32x4{0.f, 0.f, 0.f, 0.f};
    int xrow = wave * 16 + lr;
#pragma unroll
    for (int ks = 0; ks < K / 32; ++ks) {
        bf16x8 xf = *(const bf16x8*)(smem + xrow * RB + ((((ks * 32 + g * 8) * 2)) ^ ((xrow & 7) << 4)));
#pragma unroll
        for (int ob = 0; ob < M / 16; ++ob) {
            bf16x8 wf = *(const bf16x8*)(W + (size_t)(ob * 16 + lr) * K + ks * 32 + g * 8);
            if constexpr (MODE == 0) acc[ob] = mfma16(xf, wf, acc[ob]);
            else                     acc[ob] = mfma16(wf, xf, acc[ob]);
        }
    }
    if constexpr (MODE == 0) {
        bf16_t* out = (bf16_t*)outp;
#pragma unroll
        for (int ob = 0; ob < M / 16; ++ob) {
            int o = ob * 16 + lr;
            float bs = bias[o];
#pragma unroll
            for (int r = 0; r < 4; r++) {
                size_t n = (size_t)b * NPOS + n0 + wave * 16 + g * 4 + r;
                out[n * M + o] = (bf16_t)((acc[ob][r] + bs) * scale);
            }
        }
    } else {
#pragma unroll
        for (int ob = 0; ob < M / 16; ++ob) {
#pragma unroll
            for (int r = 0; r < 4; r++) {
                int o = ob * 16 + g * 4 + r;
                size_t idx = ((size_t)b * M + o) * NPOS + n0 + wave * 16 + lr;
                float v = acc[ob][r] + bias[o];
                if constexpr (MODE == 1) ((bf16_t*)outp)[idx] = (bf16_t)v;
                else                     ((float*)outp)[idx] = v + resid[idx];
            }
        }
    }
}

// ---------------- fused flash attention, 32x32 swapped-QK^T ----------------
// Qt,Kt: [B][N][D] bf16 (Q pre-scaled). V: [B][D][N] bf16. Ot: [B][N][D] bf16.
// Block: 4 waves x 32 q-rows = 128 q-rows. KVBLK=64, K/V double-buffered in LDS.
template<int D>
__device__ __forceinline__ void attn32(const bf16_t* __restrict__ Qt, const bf16_t* __restrict__ Kt,
                                       const bf16_t* __restrict__ V, bf16_t* __restrict__ Ot,
                                       int b, int qtile, char* smem, int tid)
{
    constexpr int RB  = D * 2;     // K tile row bytes
    constexpr int KB  = 64 * RB;   // K tile bytes
    constexpr int VBY = D * 128;   // V tile bytes ([D][64 keys])
    char* K0 = smem;
    char* K1 = smem + KB;
    char* V0 = smem + 2 * KB;
    char* V1 = smem + 2 * KB + VBY;

    int w = tid >> 6, lane = tid & 63;
    int qcol = lane & 31, hi = lane >> 5;
    int q0 = qtile * 128 + w * 32;

    // Q fragments in registers (B-operand: col=q, k-rows hi*8+j)
    bf16x8 qf[D / 16];
    const bf16_t* qp = Qt + ((size_t)b * NPOS + q0 + qcol) * D + hi * 8;
#pragma unroll
    for (int ks = 0; ks < D / 16; ++ks) qf[ks] = *(const bf16x8*)(qp + ks * 16);

    f32x16 acc[D / 32];
#pragma unroll
    for (int cb = 0; cb < D / 32; ++cb)
#pragma unroll
        for (int i = 0; i < 16; ++i) acc[cb][i] = 0.f;
    float m_c = -1e30f, l_c = 0.f;

    const char* kg = (const char*)(Kt + (size_t)b * NPOS * D);
    const char* vg = (const char*)(V + (size_t)b * D * NPOS);

    stage_swz<RB, KB / 4096>(K0, kg, RB, w, lane);
    stage_swz<128, VBY / 4096>(V0, vg, NPOS * 2, w, lane);
    __syncthreads();

    for (int t = 0; t < 64; ++t) {
        char* Kc = (t & 1) ? K1 : K0;
        char* Vc = (t & 1) ? V1 : V0;
        if (t + 1 < 64) {
            char* Kn = (t & 1) ? K0 : K1;
            char* Vn = (t & 1) ? V0 : V1;
            stage_swz<RB, KB / 4096>(Kn, kg + (size_t)(t + 1) * KB, RB, w, lane);
            stage_swz<128, VBY / 4096>(Vn, vg + (size_t)(t + 1) * 128, NPOS * 2, w, lane);
        }

        // S^T = K·Q : rows=keys (crow(reg,hi)), cols=queries (lane&31)
        f32x16 s0, s1;
#pragma unroll
        for (int i = 0; i < 16; ++i) { s0[i] = 0.f; s1[i] = 0.f; }
#pragma unroll
        for (int ks = 0; ks < D / 16; ++ks) {
            int cbyte = ks * 32 + hi * 16;
            bf16x8 k0 = ldfrag<RB>(Kc, qcol, cbyte);
            bf16x8 k1 = ldfrag<RB>(Kc, 32 + qcol, cbyte);
            s0 = mfma32(k0, qf[ks], s0);
            s1 = mfma32(k1, qf[ks], s1);
        }

        // in-register online softmax for query q = lane&31
        float pmax = s0[0];
#pragma unroll
        for (int i = 1; i < 16; ++i) pmax = fmaxf(pmax, s0[i]);
#pragma unroll
        for (int i = 0; i < 16; ++i) pmax = fmaxf(pmax, s1[i]);
        pmax = fmaxf(pmax, __shfl_xor(pmax, 32));

        if (__any(pmax > m_c + 8.f)) {   // defer-max (T13): rare rescale path
            float mn = fmaxf(m_c, pmax);
            float fc = __expf(m_c - mn);
            m_c = mn; l_c *= fc;
#pragma unroll
            for (int r = 0; r < 16; ++r) {
                float fr = __shfl(fc, (r & 3) + 8 * (r >> 2) + 4 * hi);
#pragma unroll
                for (int cb = 0; cb < D / 32; ++cb) acc[cb][r] *= fr;
            }
        }

        float psum = 0.f;
#pragma unroll
        for (int i = 0; i < 16; ++i) { s0[i] = __expf(s0[i] - m_c); psum += s0[i]; }
#pragma unroll
        for (int i = 0; i < 16; ++i) { s1[i] = __expf(s1[i] - m_c); psum += s1[i]; }
        psum += __shfl_xor(psum, 32);
        l_c += psum;

        // P -> bf16 A-fragments (16 packs + 8 permlane32_swap, no LDS round-trip)
        bf16x8 pa0 = MKPA(s0, 0);
        bf16x8 pa1 = MKPA(s0, 8);
        bf16x8 pa2 = MKPA(s1, 0);
        bf16x8 pa3 = MKPA(s1, 8);

        // O += P·V : B-operand from Vt LDS (row=d, cols=keys)
#pragma unroll
        for (int cb = 0; cb < D / 32; ++cb) {
            int drow = cb * 32 + qcol;
            acc[cb] = mfma32(pa0, ldfrag<128>(Vc, drow, 0  + hi * 16), acc[cb]);
            acc[cb] = mfma32(pa1, ldfrag<128>(Vc, drow, 32 + hi * 16), acc[cb]);
            acc[cb] = mfma32(pa2, ldfrag<128>(Vc, drow, 64 + hi * 16), acc[cb]);
            acc[cb] = mfma32(pa3, ldfrag<128>(Vc, drow, 96 + hi * 16), acc[cb]);
        }
        __syncthreads();
    }

    float linv = 1.f / l_c;
#pragma unroll
    for (int r = 0; r < 16; ++r) {
        int crow = (r & 3) + 8 * (r >> 2) + 4 * hi;
        float lr = __shfl(linv, crow);
        size_t nrow = (size_t)b * NPOS + q0 + crow;
#pragma unroll
        for (int cb = 0; cb < D / 32; ++cb)
            Ot[nrow * D + cb * 32 + qcol] = (bf16_t)(acc[cb][r] * lr);
    }
}

__global__ __launch_bounds__(256, 1) void k_attn32(const bf16_t* QtA, const bf16_t* KtA, const bf16_t* VA, bf16_t* OtA,
                                                   const bf16_t* QtB, const bf16_t* KtB, const bf16_t* VB, bf16_t* OtB)
{
    extern __shared__ char smem[];
    int bid = blockIdx.x, tid = threadIdx.x;
    if (bid < 128) attn32<128>(QtA, KtA, VA, OtA, bid >> 5, bid & 31, smem, tid);
    else { int r = bid - 128; attn32<64>(QtB, KtB, VB, OtB, r >> 5, r & 31, smem, tid); }
}

extern "C" void kernel_launch(void* const* d_in, const int* in_sizes, int n_in,
                              void* d_out, int out_size, void* d_ws, size_t ws_size,
                              hipStream_t stream)
{
    (void)in_sizes; (void)n_in; (void)out_size; (void)ws_size;
    const float* f2d = (const float*)d_in[0];
    const float* f3d = (const float*)d_in[1];
    const float* wqA = (const float*)d_in[2];  const float* bqA = (const float*)d_in[3];
    const float* wkA = (const float*)d_in[4];  const float* bkA = (const float*)d_in[5];
    const float* wvA = (const float*)d_in[6];  const float* bvA = (const float*)d_in[7];
    const float* wpA = (const float*)d_in[8];  const float* bpA = (const float*)d_in[9];
    const float* wqB = (const float*)d_in[10]; const float* bqB = (const float*)d_in[11];
    const float* wkB = (const float*)d_in[12]; const float* bkB = (const float*)d_in[13];
    const float* wvB = (const float*)d_in[14]; const float* bvB = (const float*)d_in[15];
    const float* wpB = (const float*)d_in[16]; const float* bpB = (const float*)d_in[17];

    char* ws = (char*)d_ws;
    bf16_t* ft2d = (bf16_t*)(ws);                // [B][N][256]  8388608 B
    bf16_t* ft3d = (bf16_t*)(ws + 8388608);      // [B][N][128]  4194304 B
    bf16_t* wbf  = (bf16_t*)(ws + 12582912);     // 147456 elems
    bf16_t* QtA  = (bf16_t*)(ws + 12877824);     // [B][N][128]
    bf16_t* KtA_ = (bf16_t*)(ws + 17072128);
    bf16_t* VA_  = (bf16_t*)(ws + 21266432);     // [B][128][N]
    bf16_t* QtB  = (bf16_t*)(ws + 25460736);     // [B][N][64]
    bf16_t* KtB_ = (bf16_t*)(ws + 27557888);
    bf16_t* VB_  = (bf16_t*)(ws + 29655040);     // [B][64][N]
    bf16_t* OtA  = (bf16_t*)(ws + 31752192);     // [B][N][128]
    bf16_t* OtB  = (bf16_t*)(ws + 35946496);     // [B][N][64]

    k_transpose<<<1536, 256, 0, stream>>>(f2d, f3d, ft2d, ft3d);
    k_weights<<<576, 256, 0, stream>>>(wqA, wkA, wvA, wpA, wqB, wkB, wvB, wpB, wbf);

    const float sA = 0.08838834764831845f;  // 128^-0.5
    const float sB = 0.125f;                // 64^-0.5

    k_proj<256, 128, 0><<<256, 256, 32768, stream>>>(ft2d, wbf +      0, bqA, sA,  nullptr, QtA);
    k_proj<128, 128, 0><<<256, 256, 16384, stream>>>(ft3d, wbf +  32768, bkA, 1.f, nullptr, KtA_);
    k_proj<128, 128, 1><<<256, 256, 16384, stream>>>(ft3d, wbf +  49152, bvA, 1.f, nullptr, VA_);
    k_proj<128,  64, 0><<<256, 256, 16384, stream>>>(ft3d, wbf +  98304, bqB, sB,  nullptr, QtB);
    k_proj<256,  64, 0><<<256, 256, 32768, stream>>>(ft2d, wbf + 106496, bkB, 1.f, nullptr, KtB_);
    k_proj<256,  64, 1><<<256, 256, 32768, stream>>>(ft2d, wbf + 122880, bvB, 1.f, nullptr, VB_);

    k_attn32<<<256, 256, 65536, stream>>>(QtA, KtA_, VA_, OtA, QtB, KtB_, VB_, OtB);

    k_proj<128, 256, 2><<<256, 256, 16384, stream>>>(OtA, wbf +  65536, bpA, 1.f, f2d, (float*)d_out);
    k_proj< 64, 128, 2><<<256, 256,  8192, stream>>>(OtB, wbf + 139264, bpB, 1.f, f3d, (float*)d_out + 4194304);
}

// Round 4
// 186.710 us; speedup vs baseline: 1.1663x; 1.0483x over previous
//
#include <hip/hip_runtime.h>
#include <hip/hip_bf16.h>
#include <math.h>

typedef __bf16 bf16_t;
typedef __bf16 bf16x8 __attribute__((ext_vector_type(8)));
typedef float f32x4 __attribute__((ext_vector_type(4)));
typedef float f32x16 __attribute__((ext_vector_type(16)));
typedef unsigned u32x2 __attribute__((ext_vector_type(2)));

#define NPOS 4096
#define LOG2E 1.4426950408889634f

__device__ __forceinline__ f32x4 mfma16(bf16x8 a, bf16x8 b, f32x4 c) {
    return __builtin_amdgcn_mfma_f32_16x16x32_bf16(a, b, c, 0, 0, 0);
}
__device__ __forceinline__ f32x16 mfma32(bf16x8 a, bf16x8 b, f32x16 c) {
    return __builtin_amdgcn_mfma_f32_32x32x16_bf16(a, b, c, 0, 0, 0);
}

typedef __attribute__((address_space(1))) const unsigned gas_u32;
typedef __attribute__((address_space(3))) unsigned las_u32;

__device__ __forceinline__ void gl_lds16(const char* g, char* l) {
    __builtin_amdgcn_global_load_lds((gas_u32*)g, (las_u32*)l, 16, 0, 0);
}

// ---- LDS tile layout: 256-byte rows, swizzle S(row) = (row&15)<<4 (2-way max) ----
// K tiles are contiguous in global: linear LDS byte j holds global byte j ^ S(j>>8).
template<int BYTES>
__device__ __forceinline__ void stageK(char* lds, const char* g, int wq, int lane) {
    constexpr int NC = BYTES / 4096;   // chunks per wave (4 waves per half)
#pragma unroll
    for (int c = 0; c < NC; ++c) {
        int j = (wq * NC + c) * 1024 + lane * 16;
        int src = j ^ (((j >> 8) & 15) << 4);
        gl_lds16(g + src, lds + j);
    }
}
// V tiles: LDS row = pair of d-rows: col = (d&1)*128 + key*2; global stride 8192 B.
template<int BYTES>
__device__ __forceinline__ void stageV(char* lds, const char* g, int wq, int lane) {
    constexpr int NC = BYTES / 4096;
#pragma unroll
    for (int c = 0; c < NC; ++c) {
        int j = (wq * NC + c) * 1024 + lane * 16;
        int row = j >> 8;
        int col = (j & 255) ^ ((row & 15) << 4);
        int d = (row << 1) | (col >> 7);
        gl_lds16(g + d * (NPOS * 2) + (col & 127), lds + j);
    }
}

template<int D>
__device__ __forceinline__ bf16x8 ldK(const char* lds, int key, int dbyte) {
    if constexpr (D == 128) {
        return *(const bf16x8*)(lds + key * 256 + (dbyte ^ ((key & 15) << 4)));
    } else {
        int row = key >> 1;
        int col = ((key & 1) << 7) | dbyte;
        return *(const bf16x8*)(lds + row * 256 + (col ^ ((row & 15) << 4)));
    }
}
__device__ __forceinline__ bf16x8 ldV(const char* lds, int d, int kbyte) {
    int row = d >> 1;
    int col = ((d & 1) << 7) | kbyte;
    return *(const bf16x8*)(lds + row * 256 + (col ^ ((row & 15) << 4)));
}

__device__ __forceinline__ unsigned pkbf(float a, float b) {
    union { bf16_t h[2]; unsigned u; } t;
    t.h[0] = (bf16_t)a; t.h[1] = (bf16_t)b;
    return t.u;
}

// P -> PV A-fragment (16 cvt-packs + 8 permlane32_swap), verified in r3.
#define MKPA(sb, base) ({                                                   \
    unsigned a0_ = pkbf((sb)[(base)+0], (sb)[(base)+1]);                    \
    unsigned a1_ = pkbf((sb)[(base)+2], (sb)[(base)+3]);                    \
    unsigned a2_ = pkbf((sb)[(base)+4], (sb)[(base)+5]);                    \
    unsigned a3_ = pkbf((sb)[(base)+6], (sb)[(base)+7]);                    \
    u32x2 r0_ = __builtin_amdgcn_permlane32_swap(a2_, a0_, false, false);   \
    u32x2 r1_ = __builtin_amdgcn_permlane32_swap(a3_, a1_, false, false);   \
    union { unsigned u[4]; bf16x8 v; } pu_;                                 \
    pu_.u[0] = r0_.y; pu_.u[1] = r1_.y; pu_.u[2] = r0_.x; pu_.u[3] = r1_.x; \
    pu_.v; })

// ---------------- transpose + fp32->bf16 convert ----------------
__global__ __launch_bounds__(256) void k_transpose(const float* __restrict__ s2d,
                                                   const float* __restrict__ s3d,
                                                   bf16_t* __restrict__ d2d,
                                                   bf16_t* __restrict__ d3d)
{
    __shared__ float tile[64][65];
    int bid = blockIdx.x, tid = threadIdx.x;
    const float* src; bf16_t* dst; int C, b, c0, n0;
    if (bid < 1024) { src = s2d; dst = d2d; C = 256; b = bid >> 8; c0 = ((bid >> 6) & 3) << 6; n0 = (bid & 63) << 6; }
    else { int r = bid - 1024; src = s3d; dst = d3d; C = 128; b = r >> 7; c0 = ((r >> 6) & 1) << 6; n0 = (r & 63) << 6; }
    const float* sp = src + ((size_t)b * C + c0) * NPOS + n0;
#pragma unroll
    for (int i = 0; i < 16; i++) {
        int idx = tid + i * 256; int c = idx >> 6, n = idx & 63;
        tile[c][n] = sp[(size_t)c * NPOS + n];
    }
    __syncthreads();
    bf16_t* dp = dst + ((size_t)b * NPOS + n0) * C + c0;
#pragma unroll
    for (int i = 0; i < 16; i++) {
        int idx = tid + i * 256; int n = idx >> 6, c = idx & 63;
        dp[(size_t)n * C + c] = (bf16_t)tile[c][n];
    }
}

// ---------------- weight fp32->bf16 ----------------
__global__ __launch_bounds__(256) void k_weights(const float* w0, const float* w1, const float* w2, const float* w3,
                                                 const float* w4, const float* w5, const float* w6, const float* w7,
                                                 bf16_t* dst)
{
    int i = blockIdx.x * 256 + threadIdx.x;
    if      (i <  32768) dst[i] = (bf16_t)w0[i];
    else if (i <  49152) dst[i] = (bf16_t)w1[i - 32768];
    else if (i <  65536) dst[i] = (bf16_t)w2[i - 49152];
    else if (i <  98304) dst[i] = (bf16_t)w3[i - 65536];
    else if (i < 106496) dst[i] = (bf16_t)w4[i - 98304];
    else if (i < 122880) dst[i] = (bf16_t)w5[i - 106496];
    else if (i < 139264) dst[i] = (bf16_t)w6[i - 122880];
    else if (i < 147456) dst[i] = (bf16_t)w7[i - 139264];
}

// ---------------- projection GEMM (unchanged from r3) ----------------
template<int K, int M, int MODE>
__global__ __launch_bounds__(256, 2) void k_proj(const bf16_t* __restrict__ Xt,
                                                 const bf16_t* __restrict__ W,
                                                 const float* __restrict__ bias,
                                                 float scale,
                                                 const float* __restrict__ resid,
                                                 void* __restrict__ outp)
{
    extern __shared__ char smem[];
    constexpr int RB = K * 2;
    int bid = blockIdx.x, tid = threadIdx.x;
    int b = bid >> 6, n0 = (bid & 63) << 6;
    int wave = tid >> 6, lane = tid & 63, g = lane >> 4, lr = lane & 15;

    {
        const char* src = (const char*)(Xt + ((size_t)b * NPOS + n0) * K);
#pragma unroll
        for (int j0 = 0; j0 < 64 * RB; j0 += 4096) {
            int j = j0 + tid * 16;
            int row = j / RB;
            int col = j & (RB - 1);
            float4 v = *(const float4*)(src + (size_t)row * RB + col);
            *(float4*)(smem + row * RB + (col ^ ((row & 7) << 4))) = v;
        }
    }
    __syncthreads();

    f32x4 acc[M / 16];
#pragma unroll
    for (int ob = 0; ob < M / 16; ++ob) acc[ob] = f32x4{0.f, 0.f, 0.f, 0.f};
    int xrow = wave * 16 + lr;
#pragma unroll
    for (int ks = 0; ks < K / 32; ++ks) {
        bf16x8 xf = *(const bf16x8*)(smem + xrow * RB + ((((ks * 32 + g * 8) * 2)) ^ ((xrow & 7) << 4)));
#pragma unroll
        for (int ob = 0; ob < M / 16; ++ob) {
            bf16x8 wf = *(const bf16x8*)(W + (size_t)(ob * 16 + lr) * K + ks * 32 + g * 8);
            if constexpr (MODE == 0) acc[ob] = mfma16(xf, wf, acc[ob]);
            else                     acc[ob] = mfma16(wf, xf, acc[ob]);
        }
    }
    if constexpr (MODE == 0) {
        bf16_t* out = (bf16_t*)outp;
#pragma unroll
        for (int ob = 0; ob < M / 16; ++ob) {
            int o = ob * 16 + lr;
            float bs = bias[o];
#pragma unroll
            for (int r = 0; r < 4; r++) {
                size_t n = (size_t)b * NPOS + n0 + wave * 16 + g * 4 + r;
                out[n * M + o] = (bf16_t)((acc[ob][r] + bs) * scale);
            }
        }
    } else {
#pragma unroll
        for (int ob = 0; ob < M / 16; ++ob) {
#pragma unroll
            for (int r = 0; r < 4; r++) {
                int o = ob * 16 + g * 4 + r;
                size_t idx = ((size_t)b * M + o) * NPOS + n0 + wave * 16 + lr;
                float v = acc[ob][r] + bias[o];
                if constexpr (MODE == 1) ((bf16_t*)outp)[idx] = (bf16_t)v;
                else                     ((float*)outp)[idx] = v + resid[idx];
            }
        }
    }
}

// ---------------- fused flash attention: 8 waves, in-block KV-split ----------------
// Waves 0-3: queries wq*32, KV tiles 0-31.  Waves 4-7: same queries, tiles 32-63.
// Exact (m,l,acc) merge via LDS at the end.  Softmax in exp2 domain (Q pre-scaled
// by D^-0.5 * log2e).
template<int D>
__device__ __forceinline__ void attn8(const bf16_t* __restrict__ Qt, const bf16_t* __restrict__ Kt,
                                      const bf16_t* __restrict__ V, bf16_t* __restrict__ Ot,
                                      int b, int qtile, char* smem, int tid)
{
    constexpr int KB = 64 * D * 2;   // K tile bytes (A:16K, B:8K)
    constexpr int VB = D * 128;      // V tile bytes (A:16K, B:8K)
    int w = tid >> 6, lane = tid & 63;
    int wq = w & 3, half = w >> 2;
    int qcol = lane & 31, hi = lane >> 5;
    int q0 = qtile * 128 + wq * 32;

    char* Kbuf[2]; char* Vbuf[2];
#pragma unroll
    for (int u = 0; u < 2; ++u) {
        char* base = smem + (half * 2 + u) * (KB + VB);
        Kbuf[u] = base; Vbuf[u] = base + KB;
    }

    // Q fragments in registers (B-operand: col=q, k-rows hi*8+j)
    bf16x8 qf[D / 16];
    const bf16_t* qp = Qt + ((size_t)b * NPOS + q0 + qcol) * D + hi * 8;
#pragma unroll
    for (int ks = 0; ks < D / 16; ++ks) qf[ks] = *(const bf16x8*)(qp + ks * 16);

    f32x16 acc[D / 32];
#pragma unroll
    for (int cb = 0; cb < D / 32; ++cb)
#pragma unroll
        for (int i = 0; i < 16; ++i) acc[cb][i] = 0.f;
    float m_c = -1e30f, l_c = 0.f;

    const char* kg = (const char*)(Kt + (size_t)b * NPOS * D);
    const char* vg = (const char*)(V + (size_t)b * D * NPOS);

    int t0 = half * 32;
    stageK<KB>(Kbuf[0], kg + (size_t)t0 * KB, wq, lane);
    stageV<VB>(Vbuf[0], vg + (size_t)t0 * 128, wq, lane);
    __syncthreads();

    for (int tl = 0; tl < 32; ++tl) {
        char* Kc = Kbuf[tl & 1];
        char* Vc = Vbuf[tl & 1];
        if (tl + 1 < 32) {
            stageK<KB>(Kbuf[(tl + 1) & 1], kg + (size_t)(t0 + tl + 1) * KB, wq, lane);
            stageV<VB>(Vbuf[(tl + 1) & 1], vg + (size_t)(t0 + tl + 1) * 128, wq, lane);
        }

        // S^T = K·Q : rows=keys, cols=queries (lane&31)
        f32x16 s0, s1;
#pragma unroll
        for (int i = 0; i < 16; ++i) { s0[i] = 0.f; s1[i] = 0.f; }
        __builtin_amdgcn_s_setprio(1);
#pragma unroll
        for (int ks = 0; ks < D / 16; ++ks) {
            int dbyte = ks * 32 + hi * 16;
            bf16x8 k0 = ldK<D>(Kc, qcol, dbyte);
            bf16x8 k1 = ldK<D>(Kc, 32 + qcol, dbyte);
            s0 = mfma32(k0, qf[ks], s0);
            s1 = mfma32(k1, qf[ks], s1);
        }
        __builtin_amdgcn_s_setprio(0);

        // in-register online softmax (exp2 domain) for query q = lane&31
        float pmax = s0[0];
#pragma unroll
        for (int i = 1; i < 16; ++i) pmax = fmaxf(pmax, s0[i]);
#pragma unroll
        for (int i = 0; i < 16; ++i) pmax = fmaxf(pmax, s1[i]);
        pmax = fmaxf(pmax, __shfl_xor(pmax, 32));

        if (__any(pmax > m_c + 11.54156f)) {   // defer-max (T13), 8 nats in exp2 domain
            float mn = fmaxf(m_c, pmax);
            float fc = exp2f(m_c - mn);
            m_c = mn; l_c *= fc;
#pragma unroll
            for (int r = 0; r < 16; ++r) {
                float fr = __shfl(fc, (r & 3) + 8 * (r >> 2) + 4 * hi);
#pragma unroll
                for (int cb = 0; cb < D / 32; ++cb) acc[cb][r] *= fr;
            }
        }

        float psum = 0.f;
#pragma unroll
        for (int i = 0; i < 16; ++i) { s0[i] = exp2f(s0[i] - m_c); psum += s0[i]; }
#pragma unroll
        for (int i = 0; i < 16; ++i) { s1[i] = exp2f(s1[i] - m_c); psum += s1[i]; }
        psum += __shfl_xor(psum, 32);
        l_c += psum;

        bf16x8 pa0 = MKPA(s0, 0);
        bf16x8 pa1 = MKPA(s0, 8);
        bf16x8 pa2 = MKPA(s1, 0);
        bf16x8 pa3 = MKPA(s1, 8);

        __builtin_amdgcn_s_setprio(1);
#pragma unroll
        for (int cb = 0; cb < D / 32; ++cb) {
            int d = cb * 32 + qcol;
            acc[cb] = mfma32(pa0, ldV(Vc, d, 0  + hi * 16), acc[cb]);
            acc[cb] = mfma32(pa1, ldV(Vc, d, 32 + hi * 16), acc[cb]);
            acc[cb] = mfma32(pa2, ldV(Vc, d, 64 + hi * 16), acc[cb]);
            acc[cb] = mfma32(pa3, ldV(Vc, d, 96 + hi * 16), acc[cb]);
        }
        __builtin_amdgcn_s_setprio(0);
        __syncthreads();
    }

    // ---- exact merge of the two KV halves via LDS ----
    float* exch = (float*)smem;          // K/V buffers dead now
    // acc area: wq*4096 + (cb*16+r)*64 + lane   (<= 16384 floats = 64KB)
    // m/l area: 24576 + wq*64 + {0,32} + qcol   (96KB offset)
    if (half == 1) {
        if (lane < 32) {
            exch[24576 + wq * 64 + lane]      = m_c;
            exch[24576 + wq * 64 + 32 + lane] = l_c;
        }
#pragma unroll
        for (int cb = 0; cb < D / 32; ++cb)
#pragma unroll
            for (int r = 0; r < 16; ++r)
                exch[wq * 4096 + (cb * 16 + r) * 64 + lane] = acc[cb][r];
    }
    __syncthreads();
    if (half == 0) {
        float m2 = exch[24576 + wq * 64 + qcol];
        float l2 = exch[24576 + wq * 64 + 32 + qcol];
        float ms = fmaxf(m_c, m2);
        float f1 = exp2f(m_c - ms), f2 = exp2f(m2 - ms);
        float linv = 1.f / (f1 * l_c + f2 * l2);
        float c1 = f1 * linv, c2 = f2 * linv;
#pragma unroll
        for (int r = 0; r < 16; ++r) {
            int crow = (r & 3) + 8 * (r >> 2) + 4 * hi;
            float g1 = __shfl(c1, crow);
            float g2 = __shfl(c2, crow);
            size_t nrow = (size_t)b * NPOS + q0 + crow;
#pragma unroll
            for (int cb = 0; cb < D / 32; ++cb) {
                float a2 = exch[wq * 4096 + (cb * 16 + r) * 64 + lane];
                Ot[nrow * D + cb * 32 + qcol] = (bf16_t)(acc[cb][r] * g1 + a2 * g2);
            }
        }
    }
}

__global__ __launch_bounds__(512, 1) void k_attn8(const bf16_t* QtA, const bf16_t* KtA, const bf16_t* VA, bf16_t* OtA,
                                                  const bf16_t* QtB, const bf16_t* KtB, const bf16_t* VB, bf16_t* OtB)
{
    extern __shared__ char smem[];
    // bid&7 = (stream*4 + batch) -> all 32 q-tiles of a group land on one XCD (T1)
    int g = blockIdx.x & 7, qtile = blockIdx.x >> 3;
    if (g < 4) attn8<128>(QtA, KtA, VA, OtA, g, qtile, smem, threadIdx.x);
    else       attn8<64>(QtB, KtB, VB, OtB, g - 4, qtile, smem, threadIdx.x);
}

extern "C" void kernel_launch(void* const* d_in, const int* in_sizes, int n_in,
                              void* d_out, int out_size, void* d_ws, size_t ws_size,
                              hipStream_t stream)
{
    (void)in_sizes; (void)n_in; (void)out_size; (void)ws_size;
    const float* f2d = (const float*)d_in[0];
    const float* f3d = (const float*)d_in[1];
    const float* wqA = (const float*)d_in[2];  const float* bqA = (const float*)d_in[3];
    const float* wkA = (const float*)d_in[4];  const float* bkA = (const float*)d_in[5];
    const float* wvA = (const float*)d_in[6];  const float* bvA = (const float*)d_in[7];
    const float* wpA = (const float*)d_in[8];  const float* bpA = (const float*)d_in[9];
    const float* wqB = (const float*)d_in[10]; const float* bqB = (const float*)d_in[11];
    const float* wkB = (const float*)d_in[12]; const float* bkB = (const float*)d_in[13];
    const float* wvB = (const float*)d_in[14]; const float* bvB = (const float*)d_in[15];
    const float* wpB = (const float*)d_in[16]; const float* bpB = (const float*)d_in[17];

    char* ws = (char*)d_ws;
    bf16_t* ft2d = (bf16_t*)(ws);                // [B][N][256]  8388608 B
    bf16_t* ft3d = (bf16_t*)(ws + 8388608);      // [B][N][128]  4194304 B
    bf16_t* wbf  = (bf16_t*)(ws + 12582912);     // 147456 elems
    bf16_t* QtA  = (bf16_t*)(ws + 12877824);     // [B][N][128]
    bf16_t* KtA_ = (bf16_t*)(ws + 17072128);
    bf16_t* VA_  = (bf16_t*)(ws + 21266432);     // [B][128][N]
    bf16_t* QtB  = (bf16_t*)(ws + 25460736);     // [B][N][64]
    bf16_t* KtB_ = (bf16_t*)(ws + 27557888);
    bf16_t* VB_  = (bf16_t*)(ws + 29655040);     // [B][64][N]
    bf16_t* OtA  = (bf16_t*)(ws + 31752192);     // [B][N][128]
    bf16_t* OtB  = (bf16_t*)(ws + 35946496);     // [B][N][64]

    k_transpose<<<1536, 256, 0, stream>>>(f2d, f3d, ft2d, ft3d);
    k_weights<<<576, 256, 0, stream>>>(wqA, wkA, wvA, wpA, wqB, wkB, wvB, wpB, wbf);

    // Q pre-scale folded with log2(e) for exp2-domain softmax
    const float sA = 0.08838834764831845f * LOG2E;  // 128^-0.5 * log2e
    const float sB = 0.125f * LOG2E;                // 64^-0.5  * log2e

    k_proj<256, 128, 0><<<256, 256, 32768, stream>>>(ft2d, wbf +      0, bqA, sA,  nullptr, QtA);
    k_proj<128, 128, 0><<<256, 256, 16384, stream>>>(ft3d, wbf +  32768, bkA, 1.f, nullptr, KtA_);
    k_proj<128, 128, 1><<<256, 256, 16384, stream>>>(ft3d, wbf +  49152, bvA, 1.f, nullptr, VA_);
    k_proj<128,  64, 0><<<256, 256, 16384, stream>>>(ft3d, wbf +  98304, bqB, sB,  nullptr, QtB);
    k_proj<256,  64, 0><<<256, 256, 32768, stream>>>(ft2d, wbf + 106496, bkB, 1.f, nullptr, KtB_);
    k_proj<256,  64, 1><<<256, 256, 32768, stream>>>(ft2d, wbf + 122880, bvB, 1.f, nullptr, VB_);

    k_attn8<<<256, 512, 131072, stream>>>(QtA, KtA_, VA_, OtA, QtB, KtB_, VB_, OtB);

    k_proj<128, 256, 2><<<256, 256, 16384, stream>>>(OtA, wbf +  65536, bpA, 1.f, f2d, (float*)d_out);
    k_proj< 64, 128, 2><<<256, 256,  8192, stream>>>(OtB, wbf + 139264, bpB, 1.f, f3d, (float*)d_out + 4194304);
}